// Round 3
// baseline (10866.417 us; speedup 1.0000x reference)
//
#include <hip/hip_runtime.h>
#include <hip/hip_bf16.h>

// 2-layer LSTM, B=64, F=128, T=1024, H=512. Output = h_T of layer 1 (64x512 fp32).
// Persistent kernel, 128 WGs x 256 thr, 1 WG/CU (VGPR-limited) -> 512 VGPR/wave.
// R3 changes vs R2 (8.0ms, 7.8us/iter):
//  - weights live in VGPRs (52 bf16x8 frags/lane), loaded once in prologue.
//    NO ds_read in the hot loop (R2: 208 ds_read_b128/CU/iter + 1.18e8 bank conflicts).
//  - flag poll split across waves 0+1: 1 flag/lane/round (R2: 2, serialized).
//  - publish via shfl_xor(16) bf16-pair pack (drops sH staging + one syncthreads).
// Unchanged (proven): 4-gen h rotation, relaxed agent sc0sc1 publish, drain+flag,
// acquire fence (buffer_inv) after barrier, bf16 matmul numerics.

#define B_ 64
#define F_ 128
#define T_ 1024
#define H_ 512
#define NWG 128

typedef __bf16 bf16x8 __attribute__((ext_vector_type(8)));
typedef float f32x4 __attribute__((ext_vector_type(4)));

__device__ __forceinline__ float sigm(float x) { return 1.0f / (1.0f + __expf(-x)); }
__device__ __forceinline__ float tanh_fast(float x) { return 1.0f - 2.0f / (__expf(2.0f * x) + 1.0f); }

// x (B,F,T) fp32 -> xT (T,B,F) bf16
__global__ __launch_bounds__(256) void transpose_x_kernel(const float* __restrict__ x,
                                                          __bf16* __restrict__ xT) {
  __shared__ float tile[F_][65];
  const int bb = blockIdx.x >> 4;
  const int tt = blockIdx.x & 15;
  const int tid = threadIdx.x;
  const int tl = tid & 63;
  const int f0 = tid >> 6;
  for (int fo = 0; fo < F_; fo += 4) {
    int f = fo + f0;
    tile[f][tl] = x[((size_t)bb * F_ + f) * T_ + tt * 64 + tl];
  }
  __syncthreads();
  const int fw = tid & 127;
  const int tg = tid >> 7;
  for (int to = 0; to < 64; to += 2) {
    int t = to + tg;
    xT[((size_t)(tt * 64 + t) * B_ + bb) * F_ + fw] = (__bf16)tile[fw][t];
  }
}

__global__ __launch_bounds__(256, 1) void lstm_persistent(
    const __bf16* __restrict__ xT,
    const float* __restrict__ Wih0, const float* __restrict__ Whh0,
    const float* __restrict__ bih0, const float* __restrict__ bhh0,
    const float* __restrict__ Wih1, const float* __restrict__ Whh1,
    const float* __restrict__ bih1, const float* __restrict__ bhh1,
    __bf16* h0_pub, __bf16* h1_pub,   // each: [4][B][H] bf16, 4-gen rotation
    unsigned* flags,                   // [NWG] x 64B lines, monotone counters
    float* __restrict__ out) {
  // LDS: only gate reshuffle staging (per-wave private). Stride 68 avoids conflicts.
  __shared__ float sG0[4][272];
  __shared__ float sG1[4][272];

  const int wg   = blockIdx.x;
  const int tid  = threadIdx.x;
  const int wv   = tid >> 6;
  const int lane = tid & 63;
  const int p    = lane >> 4;        // quad
  const int l15  = lane & 15;
  const int b    = wv * 16 + l15;    // batch (B-operand col / elementwise)
  const int ks   = p * 8;            // k offset inside a 32-chunk

  // ---- Prologue: weights -> registers (bf16 A-frags), once for all 1025 iters ----
  // A-frag row for local m = l15: grow = (l15>>2)*H + wg*4 + (l15&3)
  const int row = (l15 >> 2) * H_ + wg * 4 + (l15 & 3);
  bf16x8 w0h[16], w1i[16], w1h[16], w0i[4];
  {
    const float* s0 = Whh0 + (size_t)row * H_ + ks;
    const float* s1 = Wih1 + (size_t)row * H_ + ks;
    const float* s2 = Whh1 + (size_t)row * H_ + ks;
#pragma unroll
    for (int kc = 0; kc < 16; ++kc) {
      bf16x8 a, bb, cc;
#pragma unroll
      for (int j = 0; j < 8; ++j) {
        a[j]  = (__bf16)s0[kc * 32 + j];
        bb[j] = (__bf16)s1[kc * 32 + j];
        cc[j] = (__bf16)s2[kc * 32 + j];
      }
      w0h[kc] = a; w1i[kc] = bb; w1h[kc] = cc;
    }
    const float* si = Wih0 + (size_t)row * F_ + ks;
#pragma unroll
    for (int kc = 0; kc < 4; ++kc) {
      bf16x8 a;
#pragma unroll
      for (int j = 0; j < 8; ++j) a[j] = (__bf16)si[kc * 32 + j];
      w0i[kc] = a;
    }
  }
  float b0q[4], b1q[4];
#pragma unroll
  for (int r = 0; r < 4; ++r) {
    const int grow = p * H_ + wg * 4 + r;
    b0q[r] = bih0[grow] + bhh0[grow];
    b1q[r] = bih1[grow] + bhh1[grow];
  }

  float c0 = 0.f, c1 = 0.f;

  for (int it = 0; it <= T_; ++it) {
    const int gen_r = (it + 3) & 3;  // generation it-1
    const int gen_w = it & 3;        // generation it
    const __bf16* h0r = h0_pub + gen_r * (B_ * H_);
    const __bf16* h1r = h1_pub + gen_r * (B_ * H_);
    unsigned* h0w = (unsigned*)(h0_pub + gen_w * (B_ * H_));
    unsigned* h1w = (unsigned*)(h1_pub + gen_w * (B_ * H_));

    f32x4 acc0  = {0.f, 0.f, 0.f, 0.f};   // Whh0 * h0
    f32x4 acc0b = {0.f, 0.f, 0.f, 0.f};   // Wih0 * x_t
    f32x4 acc1a = {0.f, 0.f, 0.f, 0.f};   // Wih1 * h0
    f32x4 acc1b = {0.f, 0.f, 0.f, 0.f};   // Whh1 * h1

#pragma unroll
    for (int kc = 0; kc < 16; ++kc) {
      const int k0 = kc * 32 + ks;
      bf16x8 hb0 = *(const bf16x8*)&h0r[b * H_ + k0];
      bf16x8 hb1 = *(const bf16x8*)&h1r[b * H_ + k0];
      acc0  = __builtin_amdgcn_mfma_f32_16x16x32_bf16(w0h[kc], hb0, acc0,  0, 0, 0);
      acc1a = __builtin_amdgcn_mfma_f32_16x16x32_bf16(w1i[kc], hb0, acc1a, 0, 0, 0);
      acc1b = __builtin_amdgcn_mfma_f32_16x16x32_bf16(w1h[kc], hb1, acc1b, 0, 0, 0);
    }
    {
      const int t = (it < T_) ? it : (T_ - 1);
      const __bf16* xrow = xT + ((size_t)t * B_ + b) * F_;
#pragma unroll
      for (int kc = 0; kc < 4; ++kc) {
        bf16x8 xb = *(const bf16x8*)&xrow[kc * 32 + ks];
        acc0b = __builtin_amdgcn_mfma_f32_16x16x32_bf16(w0i[kc], xb, acc0b, 0, 0, 0);
      }
    }

    // Writer phase: lane holds C rows m=4p+r (gate p, local col r), batch l15.
#pragma unroll
    for (int r = 0; r < 4; ++r) {
      float v0 = acc0[r] + acc0b[r] + b0q[r];
      float v1 = acc1a[r] + acc1b[r] + b1q[r];
      float a0v = (p == 2) ? tanh_fast(v0) : sigm(v0);
      float a1v = (p == 2) ? tanh_fast(v1) : sigm(v1);
      sG0[wv][p * 68 + r * 16 + l15] = a0v;
      sG1[wv][p * 68 + r * 16 + l15] = a1v;
    }
    __syncthreads();

    // Reader phase: lane <-> (local col j=p, batch l15). c-update, h, publish.
    float h0v = 0.f, h1v = 0.f;
    if (it < T_) {
      float gi = sG0[wv][0 * 68 + p * 16 + l15];
      float gf = sG0[wv][1 * 68 + p * 16 + l15];
      float gg = sG0[wv][2 * 68 + p * 16 + l15];
      float go = sG0[wv][3 * 68 + p * 16 + l15];
      c0 = gf * c0 + gi * gg;
      h0v = go * tanh_fast(c0);
    }
    if (it > 0) {
      float gi = sG1[wv][0 * 68 + p * 16 + l15];
      float gf = sG1[wv][1 * 68 + p * 16 + l15];
      float gg = sG1[wv][2 * 68 + p * 16 + l15];
      float go = sG1[wv][3 * 68 + p * 16 + l15];
      c1 = gf * c1 + gi * gg;
      h1v = go * tanh_fast(c1);
    }

    if (it < T_) {
      // Pack 2 adjacent cols (lanes p, p^1) into one dword via shfl, even-p stores.
      union { __bf16 bf; unsigned short u; } u0, u1;
      u0.bf = (__bf16)h0v;
      u1.bf = (__bf16)h1v;
      unsigned o0 = (unsigned)__shfl_xor((int)(unsigned)u0.u, 16, 64);
      unsigned o1 = (unsigned)__shfl_xor((int)(unsigned)u1.u, 16, 64);
      if ((p & 1) == 0) {
        unsigned v0 = (unsigned)u0.u | (o0 << 16);
        __hip_atomic_store(h0w + b * (H_ / 2) + wg * 2 + (p >> 1), v0,
                           __ATOMIC_RELAXED, __HIP_MEMORY_SCOPE_AGENT);
        if (it > 0) {
          unsigned v1 = (unsigned)u1.u | (o1 << 16);
          __hip_atomic_store(h1w + b * (H_ / 2) + wg * 2 + (p >> 1), v1,
                             __ATOMIC_RELAXED, __HIP_MEMORY_SCOPE_AGENT);
        }
      }
    } else {
      out[b * H_ + wg * 4 + p] = h1v;   // final fp32 output
    }

    if (it != T_) {
      __syncthreads();  // drains vmcnt: publishes are at the coherence point
      const unsigned tgt = (unsigned)(it + 1);
      if (tid == 0)
        __hip_atomic_store(&flags[wg * 16], tgt, __ATOMIC_RELAXED, __HIP_MEMORY_SCOPE_AGENT);
      if (tid < 128) {   // waves 0+1: one flag line per lane
        while (__hip_atomic_load(&flags[tid * 16], __ATOMIC_RELAXED,
                                 __HIP_MEMORY_SCOPE_AGENT) < tgt)
          __builtin_amdgcn_s_sleep(1);
      }
      __syncthreads();  // all 128 WGs have arrived
      if (tid < 64)     // one acquire fence per WG (buffer_inv: drop stale L1/L2)
        __builtin_amdgcn_fence(__ATOMIC_ACQUIRE, "agent");
      __syncthreads();  // no wave issues loads before the inv
    }
  }
}

// Workspace layout:
//   [0]        flags: 128 x 64B = 8 KiB
//   [8192]     h0_pub: 4 gens x 64x512x2B = 262144 B
//   [270336]   h1_pub: 262144 B
//   [1 MiB]    xT: 16 MiB
extern "C" void kernel_launch(void* const* d_in, const int* in_sizes, int n_in,
                              void* d_out, int out_size, void* d_ws, size_t ws_size,
                              hipStream_t stream) {
  const float* x    = (const float*)d_in[0];
  const float* Wih0 = (const float*)d_in[1];
  const float* Whh0 = (const float*)d_in[2];
  const float* bih0 = (const float*)d_in[3];
  const float* bhh0 = (const float*)d_in[4];
  const float* Wih1 = (const float*)d_in[5];
  const float* Whh1 = (const float*)d_in[6];
  const float* bih1 = (const float*)d_in[7];
  const float* bhh1 = (const float*)d_in[8];
  float* out = (float*)d_out;

  char* ws = (char*)d_ws;
  unsigned* flags = (unsigned*)ws;
  __bf16* h0p = (__bf16*)(ws + 8192);
  __bf16* h1p = (__bf16*)(ws + 8192 + 4 * B_ * H_ * 2);
  __bf16* xT  = (__bf16*)(ws + (1 << 20));

  hipMemsetAsync(ws, 0, 8192 + 8 * B_ * H_ * 2, stream);

  transpose_x_kernel<<<dim3(B_ * 16), dim3(256), 0, stream>>>(x, xT);

  lstm_persistent<<<dim3(NWG), dim3(256), 0, stream>>>(
      xT, Wih0, Whh0, bih0, bhh0, Wih1, Whh1, bih1, bhh1,
      h0p, h1p, flags, out);
}

// Round 4
// 7929.824 us; speedup vs baseline: 1.3703x; 1.3703x over previous
//
#include <hip/hip_runtime.h>
#include <hip/hip_bf16.h>

// 2-layer LSTM, B=64, F=128, T=1024, H=512. Output = h_T of layer 1 (64x512 fp32).
// R4: layer-split persistent kernel. 256 WGs x 256 thr, 1 WG/CU.
//   wg in [0,128): layer-0, owns 4 h0-cols; weights Whh0(16 frags)+Wih0(4) = 80 VGPR.
//   wg in [128,256): layer-1, owns 4 h1-cols; weights Wih1(16)+Whh1(16) = 128 VGPR.
// Fixes R3's register demotion (needed 208 VGPR/lane in one WG -> compiler spilled;
// VGPR_Count=144 proved weights were NOT resident; replays thrashed L2 -> 51ms).
// Hot loop: no ds_read (weights in regs), no scratch. Barrier: 256 flag lines,
// 1 per thread. Proven R2 protocol: 4-gen h rotation, relaxed agent sc0sc1 publish,
// syncthreads vmcnt-drain, flag store+poll, wave0 acquire fence (buffer_inv).

#define B_ 64
#define F_ 128
#define T_ 1024
#define H_ 512
#define NWG 256

typedef __bf16 bf16x8 __attribute__((ext_vector_type(8)));
typedef float f32x4 __attribute__((ext_vector_type(4)));

__device__ __forceinline__ float sigm(float x) { return 1.0f / (1.0f + __expf(-x)); }
__device__ __forceinline__ float tanh_fast(float x) { return 1.0f - 2.0f / (__expf(2.0f * x) + 1.0f); }

// x (B,F,T) fp32 -> xT (T,B,F) bf16
__global__ __launch_bounds__(256) void transpose_x_kernel(const float* __restrict__ x,
                                                          __bf16* __restrict__ xT) {
  __shared__ float tile[F_][65];
  const int bb = blockIdx.x >> 4;
  const int tt = blockIdx.x & 15;
  const int tid = threadIdx.x;
  const int tl = tid & 63;
  const int f0 = tid >> 6;
  for (int fo = 0; fo < F_; fo += 4) {
    int f = fo + f0;
    tile[f][tl] = x[((size_t)bb * F_ + f) * T_ + tt * 64 + tl];
  }
  __syncthreads();
  const int fw = tid & 127;
  const int tg = tid >> 7;
  for (int to = 0; to < 64; to += 2) {
    int t = to + tg;
    xT[((size_t)(tt * 64 + t) * B_ + bb) * F_ + fw] = (__bf16)tile[fw][t];
  }
}

// Full barrier over 256 WGs: drain publishes, post flag, poll all (1 flag/thread),
// then single-wave acquire fence (buffer_inv) so stale h lines are dropped.
__device__ __forceinline__ void barrier_all(unsigned* flags, int wg, int tid, unsigned tgt) {
  __syncthreads();   // compiler emits s_waitcnt vmcnt(0) before s_barrier: publishes acked
  if (tid == 0)
    __hip_atomic_store(&flags[wg * 16], tgt, __ATOMIC_RELAXED, __HIP_MEMORY_SCOPE_AGENT);
  while (__hip_atomic_load(&flags[tid * 16], __ATOMIC_RELAXED, __HIP_MEMORY_SCOPE_AGENT) < tgt)
    __builtin_amdgcn_s_sleep(1);
  __syncthreads();   // all 256 WGs arrived
  if (tid < 64)      // one acquire fence per WG: drop stale L1/L2 before new h reads
    __builtin_amdgcn_fence(__ATOMIC_ACQUIRE, "agent");
  __syncthreads();   // no wave issues loads before the inv
}

__global__ __launch_bounds__(256, 2) void lstm_persistent(
    const __bf16* __restrict__ xT,
    const float* __restrict__ Wih0, const float* __restrict__ Whh0,
    const float* __restrict__ bih0, const float* __restrict__ bhh0,
    const float* __restrict__ Wih1, const float* __restrict__ Whh1,
    const float* __restrict__ bih1, const float* __restrict__ bhh1,
    __bf16* h0_pub, __bf16* h1_pub,   // each: [4][B][H] bf16, 4-gen rotation
    unsigned* flags,                   // [NWG] x 64B lines, monotone counters
    float* __restrict__ out) {
  __shared__ float sG[4][272];   // gate reshuffle staging, stride 68 (conflict-free)

  const int wg   = blockIdx.x;
  const int tid  = threadIdx.x;
  const int wv   = tid >> 6;
  const int lane = tid & 63;
  const int p    = lane >> 4;        // quad
  const int l15  = lane & 15;
  const int b    = wv * 16 + l15;    // batch
  const int ks   = p * 8;            // k offset inside a 32-chunk
  const int col4 = (wg & 127) * 4;   // this WG's 4 h-columns
  const int row  = (l15 >> 2) * H_ + col4 + (l15 & 3);  // A-frag gate row for m=l15

  if (wg < 128) {
    // ---------------- layer 0 ----------------
    bf16x8 wh[16], wi[4];
    {
      const float* s = Whh0 + (size_t)row * H_ + ks;
#pragma unroll
      for (int kc = 0; kc < 16; ++kc) {
        bf16x8 a;
#pragma unroll
        for (int j = 0; j < 8; ++j) a[j] = (__bf16)s[kc * 32 + j];
        wh[kc] = a;
      }
      const float* si = Wih0 + (size_t)row * F_ + ks;
#pragma unroll
      for (int kc = 0; kc < 4; ++kc) {
        bf16x8 a;
#pragma unroll
        for (int j = 0; j < 8; ++j) a[j] = (__bf16)si[kc * 32 + j];
        wi[kc] = a;
      }
    }
    float bq[4];
#pragma unroll
    for (int r = 0; r < 4; ++r) {
      const int grow = p * H_ + col4 + r;
      bq[r] = bih0[grow] + bhh0[grow];
    }

    float c0 = 0.f;
    for (int it = 0; it < T_; ++it) {
      const __bf16* h0r = h0_pub + ((it + 3) & 3) * (B_ * H_);
      unsigned* h0w = (unsigned*)(h0_pub + (it & 3) * (B_ * H_));

      f32x4 acc  = {0.f, 0.f, 0.f, 0.f};
      f32x4 accb = {0.f, 0.f, 0.f, 0.f};
#pragma unroll
      for (int kc = 0; kc < 16; ++kc) {
        bf16x8 hb0 = *(const bf16x8*)&h0r[b * H_ + kc * 32 + ks];
        acc = __builtin_amdgcn_mfma_f32_16x16x32_bf16(wh[kc], hb0, acc, 0, 0, 0);
      }
      const __bf16* xrow = xT + ((size_t)it * B_ + b) * F_;
#pragma unroll
      for (int kc = 0; kc < 4; ++kc) {
        bf16x8 xb = *(const bf16x8*)&xrow[kc * 32 + ks];
        accb = __builtin_amdgcn_mfma_f32_16x16x32_bf16(wi[kc], xb, accb, 0, 0, 0);
      }
#pragma unroll
      for (int r = 0; r < 4; ++r) {
        float v = acc[r] + accb[r] + bq[r];
        sG[wv][p * 68 + r * 16 + l15] = (p == 2) ? tanh_fast(v) : sigm(v);
      }
      __syncthreads();
      float gi = sG[wv][0 * 68 + p * 16 + l15];
      float gf = sG[wv][1 * 68 + p * 16 + l15];
      float gg = sG[wv][2 * 68 + p * 16 + l15];
      float go = sG[wv][3 * 68 + p * 16 + l15];
      c0 = gf * c0 + gi * gg;
      float h = go * tanh_fast(c0);

      union { __bf16 bf; unsigned short u; } cv; cv.bf = (__bf16)h;
      unsigned o = (unsigned)__shfl_xor((int)(unsigned)cv.u, 16, 64);
      if ((p & 1) == 0) {
        unsigned v = (unsigned)cv.u | (o << 16);
        __hip_atomic_store(h0w + b * (H_ / 2) + (col4 >> 1) + (p >> 1), v,
                           __ATOMIC_RELAXED, __HIP_MEMORY_SCOPE_AGENT);
      }
      barrier_all(flags, wg, tid, (unsigned)(it + 1));
    }
  } else {
    // ---------------- layer 1 ----------------
    bf16x8 wi[16], wh[16];
    {
      const float* s0 = Wih1 + (size_t)row * H_ + ks;
      const float* s1 = Whh1 + (size_t)row * H_ + ks;
#pragma unroll
      for (int kc = 0; kc < 16; ++kc) {
        bf16x8 a, c;
#pragma unroll
        for (int j = 0; j < 8; ++j) {
          a[j] = (__bf16)s0[kc * 32 + j];
          c[j] = (__bf16)s1[kc * 32 + j];
        }
        wi[kc] = a; wh[kc] = c;
      }
    }
    float bq[4];
#pragma unroll
    for (int r = 0; r < 4; ++r) {
      const int grow = p * H_ + col4 + r;
      bq[r] = bih1[grow] + bhh1[grow];
    }

    float c1 = 0.f;
    barrier_all(flags, wg, tid, 1u);   // end of it=0 (layer-1 idle that step)
    for (int it = 1; it <= T_; ++it) {
      const __bf16* h0r = h0_pub + ((it + 3) & 3) * (B_ * H_);
      const __bf16* h1r = h1_pub + ((it + 3) & 3) * (B_ * H_);
      unsigned* h1w = (unsigned*)(h1_pub + (it & 3) * (B_ * H_));

      f32x4 acca = {0.f, 0.f, 0.f, 0.f};
      f32x4 accc = {0.f, 0.f, 0.f, 0.f};
#pragma unroll
      for (int kc = 0; kc < 16; ++kc) {
        bf16x8 hb0 = *(const bf16x8*)&h0r[b * H_ + kc * 32 + ks];
        bf16x8 hb1 = *(const bf16x8*)&h1r[b * H_ + kc * 32 + ks];
        acca = __builtin_amdgcn_mfma_f32_16x16x32_bf16(wi[kc], hb0, acca, 0, 0, 0);
        accc = __builtin_amdgcn_mfma_f32_16x16x32_bf16(wh[kc], hb1, accc, 0, 0, 0);
      }
#pragma unroll
      for (int r = 0; r < 4; ++r) {
        float v = acca[r] + accc[r] + bq[r];
        sG[wv][p * 68 + r * 16 + l15] = (p == 2) ? tanh_fast(v) : sigm(v);
      }
      __syncthreads();
      float gi = sG[wv][0 * 68 + p * 16 + l15];
      float gf = sG[wv][1 * 68 + p * 16 + l15];
      float gg = sG[wv][2 * 68 + p * 16 + l15];
      float go = sG[wv][3 * 68 + p * 16 + l15];
      c1 = gf * c1 + gi * gg;
      float h = go * tanh_fast(c1);

      if (it < T_) {
        union { __bf16 bf; unsigned short u; } cv; cv.bf = (__bf16)h;
        unsigned o = (unsigned)__shfl_xor((int)(unsigned)cv.u, 16, 64);
        if ((p & 1) == 0) {
          unsigned v = (unsigned)cv.u | (o << 16);
          __hip_atomic_store(h1w + b * (H_ / 2) + (col4 >> 1) + (p >> 1), v,
                             __ATOMIC_RELAXED, __HIP_MEMORY_SCOPE_AGENT);
        }
        barrier_all(flags, wg, tid, (unsigned)(it + 1));
      } else {
        out[b * H_ + col4 + p] = h;   // final h1[T-1], fp32
      }
    }
  }
}

// Workspace layout:
//   [0]        flags: 256 x 64B = 16 KiB
//   [16384]    h0_pub: 4 gens x 64x512x2B = 262144 B
//   [278528]   h1_pub: 262144 B
//   [1 MiB]    xT: 16 MiB
// Zeroed region: [0, 540672).
extern "C" void kernel_launch(void* const* d_in, const int* in_sizes, int n_in,
                              void* d_out, int out_size, void* d_ws, size_t ws_size,
                              hipStream_t stream) {
  const float* x    = (const float*)d_in[0];
  const float* Wih0 = (const float*)d_in[1];
  const float* Whh0 = (const float*)d_in[2];
  const float* bih0 = (const float*)d_in[3];
  const float* bhh0 = (const float*)d_in[4];
  const float* Wih1 = (const float*)d_in[5];
  const float* Whh1 = (const float*)d_in[6];
  const float* bih1 = (const float*)d_in[7];
  const float* bhh1 = (const float*)d_in[8];
  float* out = (float*)d_out;

  char* ws = (char*)d_ws;
  unsigned* flags = (unsigned*)ws;
  __bf16* h0p = (__bf16*)(ws + 16384);
  __bf16* h1p = (__bf16*)(ws + 16384 + 4 * B_ * H_ * 2);
  __bf16* xT  = (__bf16*)(ws + (1 << 20));

  hipMemsetAsync(ws, 0, 16384 + 8 * B_ * H_ * 2, stream);

  transpose_x_kernel<<<dim3(B_ * 16), dim3(256), 0, stream>>>(x, xT);

  lstm_persistent<<<dim3(NWG), dim3(256), 0, stream>>>(
      xT, Wih0, Whh0, bih0, bhh0, Wih1, Whh1, bih1, bhh1,
      h0p, h1p, flags, out);
}